// Round 2
// baseline (434.015 us; speedup 1.0000x reference)
//
#include <hip/hip_runtime.h>
#include <hip/hip_bf16.h>

#define HW 262144            // 512*512
#define IW 512
#define TW 64
#define TH 8
#define HLW 66               // TW+2
#define HLH 10               // TH+2
#define NHALO (HLW*HLH)      // 660

// ---------------- Kernel 1: GAP of relu(conv1x1(y)) -> per-block partials ----
__global__ __launch_bounds__(256) void k_gap(
    const float* __restrict__ y, const float* __restrict__ fuse_w,
    const float* __restrict__ fuse_b, float* __restrict__ partial) {
  __shared__ float fw[80], fb[16];
  __shared__ float red[4][16];
  int tid = threadIdx.x;
  if (tid < 80) fw[tid] = fuse_w[tid];
  if (tid < 16) fb[tid] = fuse_b[tid];
  __syncthreads();

  int b = blockIdx.x >> 7;           // 8 batches
  int chunk = blockIdx.x & 127;      // 128 chunks of 2048 px
  const float* yb = y + (size_t)b * 5 * HW + chunk * 2048;

  float sums[16];
#pragma unroll
  for (int o = 0; o < 16; ++o) sums[o] = 0.f;

  for (int i = 0; i < 2048; i += 256) {
    int p = i + tid;
    float yv[5];
#pragma unroll
    for (int c = 0; c < 5; ++c) yv[c] = yb[c * HW + p];
#pragma unroll
    for (int o = 0; o < 16; ++o) {
      float a = fb[o];
#pragma unroll
      for (int c = 0; c < 5; ++c) a = fmaf(fw[o * 5 + c], yv[c], a);
      sums[o] += fmaxf(a, 0.f);
    }
  }

  int lane = tid & 63, wv = tid >> 6;
#pragma unroll
  for (int o = 0; o < 16; ++o) {
    float v = sums[o];
    for (int off = 32; off > 0; off >>= 1) v += __shfl_down(v, off);
    if (lane == 0) red[wv][o] = v;
  }
  __syncthreads();
  if (tid < 16)
    partial[blockIdx.x * 16 + tid] =
        red[0][tid] + red[1][tid] + red[2][tid] + red[3][tid];
}

// ---------------- Kernel 2: SE MLP + fold se into boundary weights ----------
__global__ void k_se(const float* __restrict__ partial,
                     const float* __restrict__ se_w1,
                     const float* __restrict__ se_w2,
                     const float* __restrict__ bd_w,
                     float* __restrict__ bd_eff) {
  int b = threadIdx.x;
  if (b >= 8) return;
  float g[16];
#pragma unroll
  for (int c = 0; c < 16; ++c) g[c] = 0.f;
  for (int chunk = 0; chunk < 128; ++chunk) {
    const float* p = partial + (b * 128 + chunk) * 16;
#pragma unroll
    for (int c = 0; c < 16; ++c) g[c] += p[c];
  }
#pragma unroll
  for (int c = 0; c < 16; ++c) g[c] *= (1.f / 262144.f);

  float h[16];
#pragma unroll
  for (int j = 0; j < 16; ++j) {
    float s = 0.f;
#pragma unroll
    for (int c = 0; c < 16; ++c) s += g[c] * se_w1[j * 16 + c];
    h[j] = fmaxf(s, 0.f);
  }
#pragma unroll
  for (int i = 0; i < 5; ++i) {
    float s = 0.f;
#pragma unroll
    for (int j = 0; j < 16; ++j) s += h[j] * se_w2[i * 16 + j];
    float se = 1.f / (1.f + expf(-s));
    bd_eff[b * 10 + i]     = bd_w[i] * se;
    bd_eff[b * 10 + 5 + i] = bd_w[5 + i] * se;
  }
}

// ---------------- Kernel 3: fused main --------------------------------------
// per block: 64x8 output tile. LDS tile buffer reused: fuse pass then x pass.
#define CONV_PASS(WOFS)                                                  \
  _Pragma("unroll 1")                                                    \
  for (int k = 0; k < 9; ++k) {                                          \
    const int kh = k / 3, kw = k % 3;                                    \
    _Pragma("unroll 4")                                                  \
    for (int ci = 0; ci < 16; ++ci) {                                    \
      float v0 = tile[ci][(ty + kh) * HLW + tx + kw];                    \
      float v1 = tile[ci][(ty + 4 + kh) * HLW + tx + kw];                \
      const float* wp = &wS[(((WOFS) + ci) * 9 + k) * 16];               \
      _Pragma("unroll")                                                  \
      for (int o = 0; o < 16; ++o) {                                     \
        float w = wp[o];                                                 \
        acc0[o] = fmaf(v0, w, acc0[o]);                                  \
        acc1[o] = fmaf(v1, w, acc1[o]);                                  \
      }                                                                  \
    }                                                                    \
  }

__global__ __launch_bounds__(256) void k_main(
    const float* __restrict__ x, const float* __restrict__ y,
    const float* __restrict__ fuse_w, const float* __restrict__ fuse_b,
    const float* __restrict__ bd_eff, const float* __restrict__ bd_b,
    const float* __restrict__ fc_w, const float* __restrict__ fc_b,
    const float* __restrict__ fm_w, const float* __restrict__ fm_b,
    const float* __restrict__ cv_w, const float* __restrict__ cv_b,
    float* __restrict__ out) {
  __shared__ float wS[32 * 9 * 16];      // [(ci*9+k)*16+o]
  __shared__ float tile[16][NHALO];
  __shared__ float s_fw[80], s_fb[16], s_bde[10], s_bdb[2], s_fm[32],
      s_fmb[2], s_cv[16], s_cvb[16], s_fcb[16];

  int tid = threadIdx.x;
  int bsel = blockIdx.z;
  int h0 = blockIdx.y * TH;
  int w0 = blockIdx.x * TW;

  if (tid < 80) s_fw[tid] = fuse_w[tid];
  else if (tid < 96)  s_fb[tid - 80]   = fuse_b[tid - 80];
  else if (tid < 106) s_bde[tid - 96]  = bd_eff[bsel * 10 + tid - 96];
  else if (tid < 108) s_bdb[tid - 106] = bd_b[tid - 106];
  else if (tid < 140) s_fm[tid - 108]  = fm_w[tid - 108];
  else if (tid < 142) s_fmb[tid - 140] = fm_b[tid - 140];
  else if (tid < 158) s_cv[tid - 142]  = cv_w[tid - 142];
  else if (tid < 174) s_cvb[tid - 158] = cv_b[tid - 158];
  else if (tid < 190) s_fcb[tid - 174] = fc_b[tid - 174];

  for (int i = tid; i < 4608; i += 256) {
    int o = i & 15, k = (i >> 4) % 9, ci = i / 144;
    wS[i] = fc_w[(o * 32 + ci) * 9 + k];
  }
  __syncthreads();

  // ---- fuse tile (concat channels 16..31) computed from global y ----
  const float* yb = y + (size_t)bsel * 5 * HW;
  for (int p = tid; p < NHALO; p += 256) {
    int hr = p / HLW, wc = p % HLW;
    int gh = h0 - 1 + hr, gw = w0 - 1 + wc;
    bool valid = (gh >= 0) & (gh < IW) & (gw >= 0) & (gw < IW);
    int gofs = gh * IW + gw;
    float yv[5];
#pragma unroll
    for (int c = 0; c < 5; ++c) yv[c] = valid ? yb[c * HW + gofs] : 0.f;
#pragma unroll
    for (int o = 0; o < 16; ++o) {
      float a = s_fb[o];
#pragma unroll
      for (int c = 0; c < 5; ++c) a = fmaf(s_fw[o * 5 + c], yv[c], a);
      tile[o][p] = valid ? fmaxf(a, 0.f) : 0.f;
    }
  }
  __syncthreads();

  int tx = tid & 63, ty = tid >> 6;   // pixels (ty,tx) and (ty+4,tx)
  float acc0[16], acc1[16];
#pragma unroll
  for (int o = 0; o < 16; ++o) { acc0[o] = 0.f; acc1[o] = 0.f; }

  CONV_PASS(16)            // fuse channels
  __syncthreads();

  // ---- x tile (concat channels 0..15) ----
  const float* xb = x + (size_t)bsel * 16 * HW;
  for (int i = tid; i < 16 * NHALO; i += 256) {
    int ci = i / NHALO, p = i - ci * NHALO;
    int hr = p / HLW, wc = p % HLW;
    int gh = h0 - 1 + hr, gw = w0 - 1 + wc;
    bool valid = (gh >= 0) & (gh < IW) & (gw >= 0) & (gw < IW);
    tile[ci][p] = valid ? xb[ci * HW + gh * IW + gw] : 0.f;
  }
  __syncthreads();

  CONV_PASS(0)             // x channels
  __syncthreads();

  // ---- epilogue ----
  auto epi = [&](const float* acc, int r) {
    int gh = h0 + r, gw = w0 + tx;
    int gofs = gh * IW + gw;
    // boundary head (1x1, se folded into bd_eff), softmax -> fg prob
    float bl0 = s_bdb[0], bl1 = s_bdb[1];
#pragma unroll
    for (int c = 0; c < 5; ++c) {
      float yv = yb[c * HW + gofs];
      bl0 = fmaf(s_bde[c], yv, bl0);
      bl1 = fmaf(s_bde[5 + c], yv, bl1);
    }
    float bscale = 1.f / (1.f + __expf(bl0 - bl1));
    // mask head: relu(conv3x3) -> 1x1 conv -> softmax fg prob
    float m0 = s_fmb[0], m1 = s_fmb[1];
#pragma unroll
    for (int o = 0; o < 16; ++o) {
      float f = fmaxf(acc[o] + s_fcb[o], 0.f);
      m0 = fmaf(s_fm[o], f, m0);
      m1 = fmaf(s_fm[16 + o], f, m1);
    }
    float mscale = 1.f / (1.f + __expf(m0 - m1));
    float sc = fminf(fmaxf(mscale + bscale, 0.f), 1.f);
#pragma unroll
    for (int o = 0; o < 16; ++o)
      out[(bsel * 16 + o) * HW + gofs] = fmaf(s_cv[o], sc, s_cvb[o]);
  };
  epi(acc0, ty);
  epi(acc1, ty + 4);
}

extern "C" void kernel_launch(void* const* d_in, const int* in_sizes, int n_in,
                              void* d_out, int out_size, void* d_ws, size_t ws_size,
                              hipStream_t stream) {
  const float* x      = (const float*)d_in[0];
  const float* y      = (const float*)d_in[1];
  const float* fuse_w = (const float*)d_in[2];
  const float* fuse_b = (const float*)d_in[3];
  const float* se_w1  = (const float*)d_in[4];
  const float* se_w2  = (const float*)d_in[5];
  const float* bd_w   = (const float*)d_in[6];
  const float* bd_b   = (const float*)d_in[7];
  const float* fc_w   = (const float*)d_in[8];
  const float* fc_b   = (const float*)d_in[9];
  const float* fm_w   = (const float*)d_in[10];
  const float* fm_b   = (const float*)d_in[11];
  const float* cv_w   = (const float*)d_in[12];
  const float* cv_b   = (const float*)d_in[13];
  float* out = (float*)d_out;

  float* partial = (float*)d_ws;          // 1024*16 floats
  float* bd_eff  = partial + 1024 * 16;   // 8*10 floats

  k_gap<<<1024, 256, 0, stream>>>(y, fuse_w, fuse_b, partial);
  k_se<<<1, 64, 0, stream>>>(partial, se_w1, se_w2, bd_w, bd_eff);
  k_main<<<dim3(8, 64, 8), 256, 0, stream>>>(x, y, fuse_w, fuse_b, bd_eff, bd_b,
                                             fc_w, fc_b, fm_w, fm_b, cv_w, cv_b,
                                             out);
}

// Round 3
// 139.041 us; speedup vs baseline: 3.1215x; 3.1215x over previous
//
#include <hip/hip_runtime.h>
#include <hip/hip_bf16.h>

#define HW 262144            // 512*512
#define IW 512
#define TW 64
#define TH 8
#define HLW 66               // TW+2
#define HLH 10               // TH+2
#define NHALO (HLW*HLH)      // 660
#define ROWU 40              // ushorts per halo-px row in LDS (80 B = 5x16B slots, 4 used)

typedef __attribute__((ext_vector_type(8))) short short8;
typedef __attribute__((ext_vector_type(4))) float f32x4;
typedef __attribute__((ext_vector_type(4))) unsigned int uint4v;

static __device__ inline unsigned int bpack2(float a, float b) {
  __hip_bfloat16 ha = __float2bfloat16(a);
  __hip_bfloat16 hb = __float2bfloat16(b);
  unsigned short ua = *reinterpret_cast<unsigned short*>(&ha);
  unsigned short ub = *reinterpret_cast<unsigned short*>(&hb);
  return (unsigned int)ua | ((unsigned int)ub << 16);
}

// ---------------- Kernel 1: GAP of relu(conv1x1(y)) -> per-block partials ----
__global__ __launch_bounds__(256) void k_gap(
    const float* __restrict__ y, const float* __restrict__ fuse_w,
    const float* __restrict__ fuse_b, float* __restrict__ partial) {
  __shared__ float fw[80], fb[16];
  __shared__ float red[4][16];
  int tid = threadIdx.x;
  if (tid < 80) fw[tid] = fuse_w[tid];
  if (tid < 16) fb[tid] = fuse_b[tid];
  __syncthreads();

  int b = blockIdx.x >> 7;           // 8 batches
  int chunk = blockIdx.x & 127;      // 128 chunks of 2048 px
  const float* yb = y + (size_t)b * 5 * HW + chunk * 2048;

  float sums[16];
#pragma unroll
  for (int o = 0; o < 16; ++o) sums[o] = 0.f;

  for (int i = 0; i < 2048; i += 256) {
    int p = i + tid;
    float yv[5];
#pragma unroll
    for (int c = 0; c < 5; ++c) yv[c] = yb[c * HW + p];
#pragma unroll
    for (int o = 0; o < 16; ++o) {
      float a = fb[o];
#pragma unroll
      for (int c = 0; c < 5; ++c) a = fmaf(fw[o * 5 + c], yv[c], a);
      sums[o] += fmaxf(a, 0.f);
    }
  }

  int lane = tid & 63, wv = tid >> 6;
#pragma unroll
  for (int o = 0; o < 16; ++o) {
    float v = sums[o];
    for (int off = 32; off > 0; off >>= 1) v += __shfl_down(v, off);
    if (lane == 0) red[wv][o] = v;
  }
  __syncthreads();
  if (tid < 16)
    partial[blockIdx.x * 16 + tid] =
        red[0][tid] + red[1][tid] + red[2][tid] + red[3][tid];
}

// ---------------- Kernel 2: SE MLP + fold se into boundary weights ----------
// 256 threads = 8 batches x 32 threads; shfl-reduce over 32 chunks each.
__global__ __launch_bounds__(256) void k_se(
    const float* __restrict__ partial, const float* __restrict__ se_w1,
    const float* __restrict__ se_w2, const float* __restrict__ bd_w,
    float* __restrict__ bd_eff) {
  int tid = threadIdx.x;
  int b = tid >> 5, sub = tid & 31;
  float g[16];
#pragma unroll
  for (int c = 0; c < 16; ++c) g[c] = 0.f;
#pragma unroll
  for (int k = 0; k < 4; ++k) {
    const float* p = partial + (b * 128 + sub + k * 32) * 16;
#pragma unroll
    for (int c = 0; c < 16; ++c) g[c] += p[c];
  }
#pragma unroll
  for (int c = 0; c < 16; ++c) {
    float v = g[c];
    v += __shfl_xor(v, 1);  v += __shfl_xor(v, 2);
    v += __shfl_xor(v, 4);  v += __shfl_xor(v, 8);
    v += __shfl_xor(v, 16);
    g[c] = v * (1.f / 262144.f);
  }
  if (sub == 0) {
    float h[16];
#pragma unroll
    for (int j = 0; j < 16; ++j) {
      float s = 0.f;
#pragma unroll
      for (int c = 0; c < 16; ++c) s += g[c] * se_w1[j * 16 + c];
      h[j] = fmaxf(s, 0.f);
    }
#pragma unroll
    for (int i = 0; i < 5; ++i) {
      float s = 0.f;
#pragma unroll
      for (int j = 0; j < 16; ++j) s += h[j] * se_w2[i * 16 + j];
      float se = 1.f / (1.f + expf(-s));
      bd_eff[b * 10 + i]     = bd_w[i] * se;
      bd_eff[b * 10 + 5 + i] = bd_w[5 + i] * se;
    }
  }
}

// ---------------- Kernel 2b: repack fc_w -> wTab[s][oc][ci] bf16 ------------
__global__ void k_prep(const float* __restrict__ fc_w,
                       unsigned short* __restrict__ wTab) {
  int i = blockIdx.x * 256 + threadIdx.x;   // (s*16+oc)*32+ci, 4608 total
  if (i < 4608) {
    int ci = i & 31, rest = i >> 5;
    int oc = rest & 15, s = rest >> 4;
    float v = fc_w[(oc * 32 + ci) * 9 + s];
    __hip_bfloat16 h = __float2bfloat16(v);
    wTab[i] = *reinterpret_cast<unsigned short*>(&h);
  }
}

// ---------------- Kernel 3: fused main (MFMA implicit-GEMM conv) ------------
__global__ __launch_bounds__(256) void k_main(
    const float* __restrict__ x, const float* __restrict__ y,
    const float* __restrict__ fuse_w, const float* __restrict__ fuse_b,
    const unsigned short* __restrict__ wTab,
    const float* __restrict__ bd_eff, const float* __restrict__ bd_b,
    const float* __restrict__ fc_b,
    const float* __restrict__ fm_w, const float* __restrict__ fm_b,
    const float* __restrict__ cv_w, const float* __restrict__ cv_b,
    float* __restrict__ out) {
  __shared__ unsigned short tile[NHALO * ROWU];   // 52800 B
  __shared__ float s_fw[80], s_fb[16], s_bde[10], s_bdb[2], s_fm[32],
      s_fmb[2], s_cv[16], s_cvb[16], s_fcb[16];

  int tid = threadIdx.x;
  int bsel = blockIdx.z;
  int h0 = blockIdx.y * TH;
  int w0 = blockIdx.x * TW;

  if (tid < 80) s_fw[tid] = fuse_w[tid];
  else if (tid < 96)  s_fb[tid - 80]   = fuse_b[tid - 80];
  else if (tid < 106) s_bde[tid - 96]  = bd_eff[bsel * 10 + tid - 96];
  else if (tid < 108) s_bdb[tid - 106] = bd_b[tid - 106];
  else if (tid < 140) s_fm[tid - 108]  = fm_w[tid - 108];
  else if (tid < 142) s_fmb[tid - 140] = fm_b[tid - 140];
  else if (tid < 158) s_cv[tid - 142]  = cv_w[tid - 142];
  else if (tid < 174) s_cvb[tid - 158] = cv_b[tid - 158];
  else if (tid < 190) s_fcb[tid - 174] = fc_b[tid - 174];

  int lane = tid & 63, wv = tid >> 6;
  int l15 = lane & 15, q = lane >> 4;

  // A-fragments: lane l -> oc=l15, ci = q*8+j, for each of 9 (kh,kw) steps
  short8 afrag[9];
#pragma unroll
  for (int s = 0; s < 9; ++s)
    afrag[s] = *reinterpret_cast<const short8*>(wTab + (s * 16 + l15) * 32 + q * 8);

  __syncthreads();   // scalar tables ready (needed by staging's s_fw/s_fb)

  // ---- stage halo tile: ch 0..15 = x (bf16), ch 16..31 = fuse (bf16) ----
  const float* yb = y + (size_t)bsel * 5 * HW;
  const float* xb = x + (size_t)bsel * 16 * HW;
  for (int p = tid; p < NHALO; p += 256) {
    int hr = p / HLW, wc = p - hr * HLW;
    int gh = h0 - 1 + hr, gw = w0 - 1 + wc;
    bool valid = (gh >= 0) & (gh < IW) & (gw >= 0) & (gw < IW);
    uint4v blk0 = {0, 0, 0, 0}, blk1 = {0, 0, 0, 0},
           blk2 = {0, 0, 0, 0}, blk3 = {0, 0, 0, 0};
    if (valid) {
      int gofs = gh * IW + gw;
      float xv[16], yv[5];
#pragma unroll
      for (int c = 0; c < 16; ++c) xv[c] = xb[c * HW + gofs];
#pragma unroll
      for (int c = 0; c < 5; ++c) yv[c] = yb[c * HW + gofs];
      float fo[16];
#pragma unroll
      for (int o = 0; o < 16; ++o) {
        float a = s_fb[o];
#pragma unroll
        for (int c = 0; c < 5; ++c) a = fmaf(s_fw[o * 5 + c], yv[c], a);
        fo[o] = fmaxf(a, 0.f);
      }
      blk0 = uint4v{bpack2(xv[0], xv[1]), bpack2(xv[2], xv[3]),
                    bpack2(xv[4], xv[5]), bpack2(xv[6], xv[7])};
      blk1 = uint4v{bpack2(xv[8], xv[9]), bpack2(xv[10], xv[11]),
                    bpack2(xv[12], xv[13]), bpack2(xv[14], xv[15])};
      blk2 = uint4v{bpack2(fo[0], fo[1]), bpack2(fo[2], fo[3]),
                    bpack2(fo[4], fo[5]), bpack2(fo[6], fo[7])};
      blk3 = uint4v{bpack2(fo[8], fo[9]), bpack2(fo[10], fo[11]),
                    bpack2(fo[12], fo[13]), bpack2(fo[14], fo[15])};
    }
    uint4v* dst = reinterpret_cast<uint4v*>(&tile[p * ROWU]);
    dst[0] = blk0; dst[1] = blk1; dst[2] = blk2; dst[3] = blk3;
  }
  __syncthreads();

  // ---- main loop: 8 pixel-groups per wave, 9 MFMA steps each ----
  const float* outb0 = nullptr; (void)outb0;
  float* outb = out + (size_t)bsel * 16 * HW;
  const char* tbase = reinterpret_cast<const char*>(tile);

#pragma unroll 1
  for (int g = 0; g < 8; ++g) {
    int row = 2 * wv + (g >> 2);
    int c0 = (g & 3) * 16;
    int hp0 = row * HLW + c0 + l15;           // kh=0,kw=0 halo px for this lane
    const char* bp = tbase + hp0 * (ROWU * 2) + q * 16;

    f32x4 acc = {0.f, 0.f, 0.f, 0.f};
#pragma unroll
    for (int kh = 0; kh < 3; ++kh) {
#pragma unroll
      for (int kw = 0; kw < 3; ++kw) {
        short8 bfr = *reinterpret_cast<const short8*>(
            bp + (kh * HLW + kw) * (ROWU * 2));
        acc = __builtin_amdgcn_mfma_f32_16x16x32_bf16(afrag[kh * 3 + kw], bfr,
                                                      acc, 0, 0, 0);
      }
    }

    // ---- epilogue for this group (all fp32) ----
    float pm0 = 0.f, pm1 = 0.f;
#pragma unroll
    for (int j = 0; j < 4; ++j) {
      int oc = q * 4 + j;
      float fv = fmaxf(acc[j] + s_fcb[oc], 0.f);
      pm0 = fmaf(s_fm[oc], fv, pm0);
      pm1 = fmaf(s_fm[16 + oc], fv, pm1);
    }
    pm0 += __shfl_xor(pm0, 16); pm0 += __shfl_xor(pm0, 32);
    pm1 += __shfl_xor(pm1, 16); pm1 += __shfl_xor(pm1, 32);
    float m0 = pm0 + s_fmb[0], m1 = pm1 + s_fmb[1];
    float mscale = 1.f / (1.f + __expf(m0 - m1));

    int gh = h0 + row, gw = w0 + c0 + l15;
    int gofs = gh * IW + gw;
    float bl0 = s_bdb[0], bl1 = s_bdb[1];
#pragma unroll
    for (int c = 0; c < 5; ++c) {
      float yv = yb[c * HW + gofs];
      bl0 = fmaf(s_bde[c], yv, bl0);
      bl1 = fmaf(s_bde[5 + c], yv, bl1);
    }
    float bscale = 1.f / (1.f + __expf(bl0 - bl1));
    float sc = fminf(fmaxf(mscale + bscale, 0.f), 1.f);
#pragma unroll
    for (int j = 0; j < 4; ++j) {
      int oc = q * 4 + j;
      outb[oc * HW + gofs] = fmaf(s_cv[oc], sc, s_cvb[oc]);
    }
  }
}

extern "C" void kernel_launch(void* const* d_in, const int* in_sizes, int n_in,
                              void* d_out, int out_size, void* d_ws, size_t ws_size,
                              hipStream_t stream) {
  const float* x      = (const float*)d_in[0];
  const float* y      = (const float*)d_in[1];
  const float* fuse_w = (const float*)d_in[2];
  const float* fuse_b = (const float*)d_in[3];
  const float* se_w1  = (const float*)d_in[4];
  const float* se_w2  = (const float*)d_in[5];
  const float* bd_w   = (const float*)d_in[6];
  const float* bd_b   = (const float*)d_in[7];
  const float* fc_w   = (const float*)d_in[8];
  const float* fc_b   = (const float*)d_in[9];
  const float* fm_w   = (const float*)d_in[10];
  const float* fm_b   = (const float*)d_in[11];
  const float* cv_w   = (const float*)d_in[12];
  const float* cv_b   = (const float*)d_in[13];
  float* out = (float*)d_out;

  float* partial = (float*)d_ws;                              // 16384 floats
  float* bd_eff  = partial + 1024 * 16;                       // 80 floats
  unsigned short* wTab =
      (unsigned short*)((char*)d_ws + (1024 * 16 + 80) * 4);  // 4608 ushort

  k_gap<<<1024, 256, 0, stream>>>(y, fuse_w, fuse_b, partial);
  k_se<<<1, 256, 0, stream>>>(partial, se_w1, se_w2, bd_w, bd_eff);
  k_prep<<<18, 256, 0, stream>>>(fc_w, wTab);
  k_main<<<dim3(8, 64, 8), 256, 0, stream>>>(x, y, fuse_w, fuse_b, wTab,
                                             bd_eff, bd_b, fc_b, fm_w, fm_b,
                                             cv_w, cv_b, out);
}